// Round 8
// baseline (131.713 us; speedup 1.0000x reference)
//
#include <hip/hip_runtime.h>
#include <hip/hip_bf16.h>

#define NV 100       // n_vars
#define HID 64       // hidden
#define NE 1000      // experts
#define NB 4096      // batch
#define ESPLIT 32    // K-split count
#define BLOBU 3648   // u32 per expert blob: [0,3584) W2 frags, [3584,3648) pk(W1,b1)
#define BUFB 14592   // bytes per LDS W2 buffer (= BLOBU*4)

typedef __attribute__((ext_vector_type(8))) short short8;   // MFMA A/B frag
typedef __attribute__((ext_vector_type(4))) float f32x4;    // MFMA C/D frag
typedef __attribute__((ext_vector_type(4))) unsigned u32x4;
typedef __attribute__((ext_vector_type(4))) unsigned short u16x4;

__device__ __align__(16) float g_bsum[NV];

__device__ __forceinline__ short cvtbf(float f) {
    return __builtin_bit_cast(short, (__bf16)f);
}
__device__ __forceinline__ unsigned short f2bf(float f) {
    return (unsigned short)__builtin_bit_cast(short, (__bf16)f);
}
__device__ __forceinline__ float bf2f(unsigned short s) {
    union { unsigned u; float f; } v; v.u = ((unsigned)s) << 16;
    return v.f;
}
__device__ __forceinline__ float bcast_lo(unsigned u) {
    union { unsigned u; float f; } v; v.u = u << 16; return v.f;
}
__device__ __forceinline__ float bcast_hi(unsigned u) {
    union { unsigned u; float f; } v; v.u = u & 0xffff0000u; return v.f;
}
__device__ __forceinline__ unsigned pkbf(float a, float b) {
    return (unsigned)f2bf(a) | ((unsigned)f2bf(b) << 16);
}

// balanced, 4-aligned expert split: 26 splits of 32, 6 splits of 28
__device__ __host__ __forceinline__ void esplit_range(int ks, int* pe0, int* pne) {
    int e0 = (ks < 26) ? 32 * ks : 832 + 28 * (ks - 26);
    int ne = (ks < 26) ? 32 : 28;
    *pe0 = e0; *pne = ne;
}

// ---------------- bias: g_bsum[v] = sum_e b2[e*NV + v] ----------------
__global__ void bias_kernel(const float* __restrict__ b2) {
    int v = blockIdx.x;
    float s = 0.f;
    for (int e = threadIdx.x; e < NE; e += 256)
        s += b2[e * NV + v];
    __shared__ float red[4];
    for (int off = 32; off; off >>= 1) s += __shfl_down(s, off, 64);
    if ((threadIdx.x & 63) == 0) red[threadIdx.x >> 6] = s;
    __syncthreads();
    if (threadIdx.x == 0) g_bsum[v] = red[0] + red[1] + red[2] + red[3];
}

// ---------------- init (fallback path only) ----------------
__global__ void init_kernel(float* __restrict__ out) {
    int idx = blockIdx.x * 256 + threadIdx.x;
    if (idx < NB * NV) out[idx] = g_bsum[idx % NV];
}

// ---------------- prepass: per-expert 14592 B blob ----------------
// W2 frag f = ksh*7+t (1 KiB): u32 at (f*256 + l*4 + q) = pk(W2[h0][v], W2[h0+1][v]),
// l = kg*16+lrow, h0 = ksh*32+kg*8+2q, v = t*16+lrow. Hot read: linear b128.
// [3584,3648): u32 j = pk(W1[e][j], b1[e][j])  (lo=W1, hi=b1).
__global__ void prepass5(const float* __restrict__ W2, const float* __restrict__ W1,
                         const float* __restrict__ b1, unsigned* __restrict__ blob) {
    __shared__ float t[HID][NV + 1];
    int e = blockIdx.x;
    const float* src = W2 + (size_t)e * (HID * NV);
    for (int i = threadIdx.x; i < HID * NV; i += 256) {
        int hh = i / NV;
        int v = i - hh * NV;
        t[hh][v] = src[i];
    }
    __syncthreads();
    unsigned* dst = blob + (size_t)e * BLOBU;
    for (int o = threadIdx.x; o < 3584; o += 256) {
        int f = o >> 8;
        int r = o & 255;
        int l = r >> 2;
        int q = r & 3;
        int ksh = f / 7, tt = f - 7 * ksh;
        int kg = l >> 4, lrow = l & 15;
        int h0 = ksh * 32 + kg * 8 + 2 * q;
        int v = tt * 16 + lrow;
        unsigned val = 0;
        if (v < NV) val = pkbf(t[h0][v], t[h0 + 1][v]);
        dst[o] = val;
    }
    if (threadIdx.x < 64) {
        int j = threadIdx.x;
        dst[3584 + j] = pkbf(W1[(size_t)e * HID + j], b1[(size_t)e * HID + j]);
    }
}

// ---------------- main: 8 waves (4M x 2N), BM=256, 16 waves/CU, dbuf blob ----------------
__global__ __launch_bounds__(512, 4) void moe8(
    const float* __restrict__ x, const unsigned* __restrict__ blob,
    float* __restrict__ part)
{
    __shared__ __align__(16) unsigned char smem[BUFB * 2 + 16384];
    // [0, 2*BUFB): W2+wpk double buffer; [2*BUFB, +16384): permuted x^T tile
    unsigned short* xts = (unsigned short*)(smem + 2 * BUFB);

    const int bid = blockIdx.x;
    const int xcd = bid & 7;
    const int jj  = bid >> 3;              // 0..63
    const int ks  = xcd * 4 + (jj & 3);    // 4 consecutive ksplits per XCD (L2 locality)
    const int mb  = jj >> 2;               // 0..15

    const int tid  = threadIdx.x;
    const int lane = tid & 63;
    const int wave = tid >> 6;             // 0..7
    const int lrow = lane & 15;
    const int kg   = lane >> 4;
    const int wm   = wave & 3;             // rows wm*64 .. +63
    const int wn   = wave >> 2;            // 0: t 0..3, 1: t 4..6

    const int row0 = mb * 256;
    int e0, ne; esplit_range(ks, &e0, &ne);

    // ---- stage x: row r -> slot wm*64 + lrow*4 + rf (so hot read is one b64) ----
    {
        int r = tid & 255, half = tid >> 8;
        int slot = ((r >> 6) & 3) * 64 + (r & 15) * 4 + ((r >> 4) & 3);
        const float* xp = x + (size_t)(row0 + r) * NE + e0;
        #pragma unroll
        for (int c4 = 0; c4 < 4; ++c4) {
            int eb = half * 16 + c4 * 4;
            if (eb < ne) {
                float4 v = *(const float4*)(xp + eb);
                xts[(eb + 0) * 256 + slot] = f2bf(v.x);
                xts[(eb + 1) * 256 + slot] = f2bf(v.y);
                xts[(eb + 2) * 256 + slot] = f2bf(v.z);
                xts[(eb + 3) * 256 + slot] = f2bf(v.w);
            }
        }
    }

    // ---- stage: one 14592 B blob -> LDS (912 x 16B chunks, 512 threads) ----
    auto stage = [&](int buf, int e) {
        const unsigned* g = blob + (size_t)e * BLOBU;
        unsigned* lbase = (unsigned*)(smem + buf * BUFB);
        __builtin_amdgcn_global_load_lds(
            (const __attribute__((address_space(1))) unsigned*)(g + tid * 4),
            (__attribute__((address_space(3))) unsigned*)(lbase + tid * 4),
            16, 0, 0);
        if (tid < 400)
            __builtin_amdgcn_global_load_lds(
                (const __attribute__((address_space(1))) unsigned*)(g + (512 + tid) * 4),
                (__attribute__((address_space(3))) unsigned*)(lbase + (512 + tid) * 4),
                16, 0, 0);
    };

    stage(0, e0);
    __syncthreads();   // buf0 + xts ready

    f32x4 acc[4][4];   // [rf][tt]; wn==1 uses tt 0..2
    #pragma unroll
    for (int rf = 0; rf < 4; ++rf)
        #pragma unroll
        for (int tt = 0; tt < 4; ++tt)
            acc[rf][tt] = (f32x4){0.f, 0.f, 0.f, 0.f};

    int cur = 0;
    for (int ei = 0; ei < ne; ++ei) {
        if (ei + 1 < ne) stage(cur ^ 1, e0 + ei + 1);   // prefetch next expert

        const unsigned char* bufc = smem + cur * BUFB;

        u16x4 xq = *(const u16x4*)&xts[ei * 256 + wm * 64 + lrow * 4];
        float xv[4];
        #pragma unroll
        for (int rf = 0; rf < 4; ++rf) xv[rf] = bf2f(xq[rf]);

        #pragma unroll
        for (int ksh = 0; ksh < 2; ++ksh) {
            // packed (W1|b1) for this lane's 8 h-values: 2 broadcast b128 reads
            const unsigned char* wpk = bufc + 14336 + ksh * 128 + kg * 32;
            u32x4 p0 = *(const u32x4*)(wpk);
            u32x4 p1 = *(const u32x4*)(wpk + 16);

            short8 afr[4];
            #pragma unroll
            for (int q = 0; q < 4; ++q) {
                float w0 = bcast_lo(p0[q]), b0 = bcast_hi(p0[q]);
                float w1 = bcast_lo(p1[q]), b1v = bcast_hi(p1[q]);
                #pragma unroll
                for (int rf = 0; rf < 4; ++rf) {
                    afr[rf][q]     = cvtbf(fmaxf(fmaf(xv[rf], w0, b0), 0.f));
                    afr[rf][q + 4] = cvtbf(fmaxf(fmaf(xv[rf], w1, b1v), 0.f));
                }
            }

            __builtin_amdgcn_s_setprio(1);
            if (wn == 0) {
                #pragma unroll
                for (int tt = 0; tt < 4; ++tt) {
                    short8 bf = *(const short8*)(bufc + ((ksh * 7 + tt) << 10) + lane * 16);
                    #pragma unroll
                    for (int rf = 0; rf < 4; ++rf)
                        acc[rf][tt] = __builtin_amdgcn_mfma_f32_16x16x32_bf16(afr[rf], bf, acc[rf][tt], 0, 0, 0);
                }
            } else {
                #pragma unroll
                for (int tt = 0; tt < 3; ++tt) {
                    short8 bf = *(const short8*)(bufc + ((ksh * 7 + 4 + tt) << 10) + lane * 16);
                    #pragma unroll
                    for (int rf = 0; rf < 4; ++rf)
                        acc[rf][tt] = __builtin_amdgcn_mfma_f32_16x16x32_bf16(afr[rf], bf, acc[rf][tt], 0, 0, 0);
                }
            }
            __builtin_amdgcn_s_setprio(0);
        }
        __syncthreads();   // next buffer landed during compute
        cur ^= 1;
    }

    // ---- epilogue: C/D col = lane&15, row = kg*4 + reg -> partials ----
    float* dst = part + (size_t)ks * (NB * NV);
    const int rowb = row0 + wm * 64 + kg * 4;
    if (wn == 0) {
        #pragma unroll
        for (int rf = 0; rf < 4; ++rf) {
            #pragma unroll
            for (int tt = 0; tt < 4; ++tt) {
                int col = tt * 16 + lrow;          // 0..63 < NV
                size_t base = (size_t)(rowb + rf * 16) * NV + col;
                #pragma unroll
                for (int r = 0; r < 4; ++r)
                    dst[base + (size_t)r * NV] = acc[rf][tt][r];
            }
        }
    } else {
        #pragma unroll
        for (int rf = 0; rf < 4; ++rf) {
            #pragma unroll
            for (int tt = 0; tt < 3; ++tt) {
                int col = (4 + tt) * 16 + lrow;
                if (col < NV) {
                    size_t base = (size_t)(rowb + rf * 16) * NV + col;
                    #pragma unroll
                    for (int r = 0; r < 4; ++r)
                        dst[base + (size_t)r * NV] = acc[rf][tt][r];
                }
            }
        }
    }
}

// ---------------- reduce: out = bias + sum_k part[k] (float4) ----------------
__global__ void reduce2(const float* __restrict__ part, float* __restrict__ out) {
    int i4 = blockIdx.x * 256 + threadIdx.x;   // < NB*NV/4 = 102400
    f32x4 s = *(const f32x4*)&g_bsum[(i4 % 25) * 4];
    size_t off = (size_t)i4 * 4;
    #pragma unroll 4
    for (int k = 0; k < ESPLIT; ++k)
        s += *(const f32x4*)&part[(size_t)k * (NB * NV) + off];
    *(f32x4*)&out[off] = s;
}

// ---------------- fallback (tiny ws): in-kernel convert + atomics ----------------
#define LDW 72
__global__ __launch_bounds__(256, 3) void moe_fallback(
    const float* __restrict__ x, const float* __restrict__ W1,
    const float* __restrict__ b1, const float* __restrict__ W2,
    float* __restrict__ dst)
{
    __shared__ unsigned short w2t[8192];
    const int tid  = threadIdx.x;
    const int lane = tid & 63;
    const int lrow = lane & 15;
    const int kg   = lane >> 4;
    const int wave = tid >> 6;
    const int row0 = blockIdx.x * 128 + wave * 32;
    const int e0 = blockIdx.y * 32;
    const int e1 = min(NE, e0 + 32);

    f32x4 acc[2][7];
    #pragma unroll
    for (int rf = 0; rf < 2; ++rf)
        #pragma unroll
        for (int t = 0; t < 7; ++t)
            acc[rf][t] = (f32x4){0.f, 0.f, 0.f, 0.f};

    const float* xr0 = x + (size_t)(row0 + lrow) * NE;
    const float* xr1 = x + (size_t)(row0 + 16 + lrow) * NE;

    for (int e = e0; e < e1; ++e) {
        __syncthreads();
        const float* src = W2 + (size_t)e * (HID * NV);
        unsigned* w2t32 = (unsigned*)w2t;
        #pragma unroll
        for (int k = 0; k < 13; ++k) {
            int i = tid + k * 256;
            if (i < (HID / 2) * NV) {
                int a3  = i / 400;
                int rem = i - a3 * 400;
                int bv  = rem >> 2;
                int c   = rem & 3;
                int hh2 = a3 * 4 + c;
                float f0 = src[(2 * hh2) * NV + bv];
                float f1 = src[(2 * hh2 + 1) * NV + bv];
                w2t32[bv * (LDW / 2) + hh2] = pkbf(f0, f1);
            }
        }
        __syncthreads();

        float xv0 = xr0[e];
        float xv1 = xr1[e];
        const float* w1p = W1 + e * HID;
        const float* b1p = b1 + e * HID;
        #pragma unroll
        for (int ksh = 0; ksh < 2; ++ksh) {
            const int hb = ksh * 32 + kg * 8;
            f32x4 w1lo = *(const f32x4*)(w1p + hb);
            f32x4 w1hi = *(const f32x4*)(w1p + hb + 4);
            f32x4 blo  = *(const f32x4*)(b1p + hb);
            f32x4 bhi  = *(const f32x4*)(b1p + hb + 4);
            short8 a0, a1;
            #pragma unroll
            for (int j = 0; j < 4; ++j) {
                a0[j]     = cvtbf(fmaxf(fmaf(xv0, w1lo[j], blo[j]), 0.f));
                a0[j + 4] = cvtbf(fmaxf(fmaf(xv0, w1hi[j], bhi[j]), 0.f));
                a1[j]     = cvtbf(fmaxf(fmaf(xv1, w1lo[j], blo[j]), 0.f));
                a1[j + 4] = cvtbf(fmaxf(fmaf(xv1, w1hi[j], bhi[j]), 0.f));
            }
            #pragma unroll
            for (int t = 0; t < 7; ++t) {
                short8 bf = *(const short8*)&w2t[(t * 16 + lrow) * LDW + hb];
                acc[0][t] = __builtin_amdgcn_mfma_f32_16x16x32_bf16(a0, bf, acc[0][t], 0, 0, 0);
                acc[1][t] = __builtin_amdgcn_mfma_f32_16x16x32_bf16(a1, bf, acc[1][t], 0, 0, 0);
            }
        }
    }

    #pragma unroll
    for (int rf = 0; rf < 2; ++rf) {
        #pragma unroll
        for (int t = 0; t < 7; ++t) {
            int col = t * 16 + lrow;
            if (col < NV) {
                size_t base = (size_t)(row0 + rf * 16 + kg * 4) * NV + col;
                #pragma unroll
                for (int r = 0; r < 4; ++r)
                    atomicAdd(&dst[base + (size_t)r * NV], acc[rf][t][r]);
            }
        }
    }
}

extern "C" void kernel_launch(void* const* d_in, const int* in_sizes, int n_in,
                              void* d_out, int out_size, void* d_ws, size_t ws_size,
                              hipStream_t stream) {
    const float* x  = (const float*)d_in[0];
    const float* W1 = (const float*)d_in[1];
    const float* b1 = (const float*)d_in[2];
    const float* W2 = (const float*)d_in[3];
    const float* b2 = (const float*)d_in[4];
    float* out = (float*)d_out;

    const size_t BLOB_BYTES = (size_t)NE * BLOBU * 4;        // 14,592,000
    const size_t PART_BYTES = (size_t)ESPLIT * NB * NV * 4;  // 52,428,800

    bias_kernel<<<NV, 256, 0, stream>>>(b2);

    if (ws_size >= BLOB_BYTES + PART_BYTES) {
        unsigned* blob = (unsigned*)d_ws;
        float* part = (float*)((char*)d_ws + BLOB_BYTES);
        prepass5<<<NE, 256, 0, stream>>>(W2, W1, b1, blob);
        moe8<<<512, 512, 0, stream>>>(x, blob, part);
        reduce2<<<(NB * NV / 4 + 255) / 256, 256, 0, stream>>>(part, out);
    } else {
        init_kernel<<<(NB * NV + 255) / 256, 256, 0, stream>>>(out);
        moe_fallback<<<dim3(NB / 128, ESPLIT), 256, 0, stream>>>(x, W1, b1, W2, out);
    }
}

// Round 9
// 81.569 us; speedup vs baseline: 1.6147x; 1.6147x over previous
//
#include <hip/hip_runtime.h>
#include <hip/hip_bf16.h>

#define NV 100        // n_vars
#define HID 64        // hidden
#define NE 1000       // experts
#define NB 4096       // batch
#define ESPLIT 32     // K-split count
#define BLOBU 3712    // u32 per expert blob: [0,3584) W2 frags, [3584,3712) W1/b1 f32
#define EXPB 14848    // bytes per expert blob (= BLOBU*4, 928 x 16B chunks)

typedef __attribute__((ext_vector_type(8))) short short8;   // MFMA A/B frag
typedef __attribute__((ext_vector_type(4))) float f32x4;    // MFMA C/D frag
typedef __attribute__((ext_vector_type(4))) unsigned short u16x4;

__device__ __align__(16) float g_bsum[NV];

__device__ __forceinline__ short cvtbf(float f) {
    return __builtin_bit_cast(short, (__bf16)f);
}
__device__ __forceinline__ unsigned short f2bf(float f) {
    return (unsigned short)__builtin_bit_cast(short, (__bf16)f);
}
__device__ __forceinline__ float bf2f(unsigned short s) {
    union { unsigned u; float f; } v; v.u = ((unsigned)s) << 16;
    return v.f;
}
__device__ __forceinline__ unsigned pkbf(float a, float b) {
    return (unsigned)f2bf(a) | ((unsigned)f2bf(b) << 16);
}

// balanced, even expert split: 26 splits of 32, 6 splits of 28 (all even)
__device__ __host__ __forceinline__ void esplit_range(int ks, int* pe0, int* pne) {
    int e0 = (ks < 26) ? 32 * ks : 832 + 28 * (ks - 26);
    int ne = (ks < 26) ? 32 : 28;
    *pe0 = e0; *pne = ne;
}

// ---------------- bias: g_bsum[v] = sum_e b2[e*NV + v] ----------------
__global__ void bias_kernel(const float* __restrict__ b2) {
    int v = blockIdx.x;
    float s = 0.f;
    for (int e = threadIdx.x; e < NE; e += 256)
        s += b2[e * NV + v];
    __shared__ float red[4];
    for (int off = 32; off; off >>= 1) s += __shfl_down(s, off, 64);
    if ((threadIdx.x & 63) == 0) red[threadIdx.x >> 6] = s;
    __syncthreads();
    if (threadIdx.x == 0) g_bsum[v] = red[0] + red[1] + red[2] + red[3];
}

// ---------------- init (fallback path only) ----------------
__global__ void init_kernel(float* __restrict__ out) {
    int idx = blockIdx.x * 256 + threadIdx.x;
    if (idx < NB * NV) out[idx] = g_bsum[idx % NV];
}

// ---------------- prepass: per-expert 14848 B blob ----------------
// W2 frag f = ksh*7+t (1 KiB): u32 at (f*256 + l*4 + q) = pk(W2[h0][v], W2[h0+1][v]),
// l = kg*16+lrow, h0 = ksh*32+kg*8+2q, v = t*16+lrow. Hot read: linear ds_read_b128.
// [3584,3712): (ksh,kg) 64B chunks = {W1[h0..h0+7], b1[h0..h0+7]} f32, h0=ksh*32+kg*8.
__global__ void prepass6(const float* __restrict__ W2, const float* __restrict__ W1,
                         const float* __restrict__ b1, unsigned* __restrict__ blob) {
    __shared__ float t[HID][NV + 1];
    int e = blockIdx.x;
    const float* src = W2 + (size_t)e * (HID * NV);
    for (int i = threadIdx.x; i < HID * NV; i += 256) {
        int hh = i / NV;
        int v = i - hh * NV;
        t[hh][v] = src[i];
    }
    __syncthreads();
    unsigned* dst = blob + (size_t)e * BLOBU;
    for (int o = threadIdx.x; o < 3584; o += 256) {
        int f = o >> 8;
        int r = o & 255;
        int l = r >> 2;
        int q = r & 3;
        int ksh = f / 7, tt = f - 7 * ksh;
        int kg = l >> 4, lrow = l & 15;
        int h0 = ksh * 32 + kg * 8 + 2 * q;
        int v = tt * 16 + lrow;
        unsigned val = 0;
        if (v < NV) val = pkbf(t[h0][v], t[h0 + 1][v]);
        dst[o] = val;
    }
    if (threadIdx.x < 128) {
        int o = threadIdx.x;
        int ksh = o >> 6, kg = (o >> 4) & 3, j = o & 15;
        int h0 = ksh * 32 + kg * 8;
        float val = (j < 8) ? W1[(size_t)e * HID + h0 + j]
                            : b1[(size_t)e * HID + h0 + (j - 8)];
        dst[3584 + o] = __builtin_bit_cast(unsigned, val);
    }
}

// ---------------- main: 4 waves x 64 rows, 2-expert phases, dbuf ----------------
__global__ __launch_bounds__(256, 2) void moe9(
    const float* __restrict__ x, const unsigned* __restrict__ blob,
    float* __restrict__ part)
{
    __shared__ __align__(16) unsigned char smem[4 * EXPB + 16384];   // 75776 B
    unsigned short* xts = (unsigned short*)(smem + 4 * EXPB);        // permuted x^T

    const int bid = blockIdx.x;
    const int xcd = bid & 7;
    const int jj  = bid >> 3;              // 0..63
    const int ks  = xcd * 4 + (jj & 3);    // 4 consecutive ksplits per XCD (L2 locality)
    const int mb  = jj >> 2;               // 0..15

    const int tid  = threadIdx.x;
    const int lane = tid & 63;
    const int wave = tid >> 6;             // 0..3, rows wave*64 .. +63
    const int lrow = lane & 15;
    const int kg   = lane >> 4;

    const int row0 = mb * 256;
    int e0, ne; esplit_range(ks, &e0, &ne);

    // ---- stage x permuted: row r -> slot (r>>6)*64 + (r&15)*4 + ((r>>4)&3) ----
    // hot read becomes one conflict-free ds_read_b64 per wave-expert
    {
        int r = tid;
        int slot = (r >> 6) * 64 + (r & 15) * 4 + ((r >> 4) & 3);
        const float* xp = x + (size_t)(row0 + r) * NE + e0;
        #pragma unroll
        for (int c4 = 0; c4 < 8; ++c4) {
            int eb = c4 * 4;
            if (eb < ne) {
                float4 v = *(const float4*)(xp + eb);
                xts[(eb + 0) * 256 + slot] = f2bf(v.x);
                xts[(eb + 1) * 256 + slot] = f2bf(v.y);
                xts[(eb + 2) * 256 + slot] = f2bf(v.z);
                xts[(eb + 3) * 256 + slot] = f2bf(v.w);
            }
        }
    }

    // ---- stage two expert blobs (29696 B = 1856 x 16B chunks) ----
    auto stage2 = [&](int buf, int e) {
        const unsigned* g = blob + (size_t)e * BLOBU;
        unsigned* lbase = (unsigned*)(smem + buf * (2 * EXPB));
        #pragma unroll
        for (int k = 0; k < 7; ++k) {
            int off = (k * 256 + tid) * 4;
            __builtin_amdgcn_global_load_lds(
                (const __attribute__((address_space(1))) unsigned*)(g + off),
                (__attribute__((address_space(3))) unsigned*)(lbase + off),
                16, 0, 0);
        }
        if (tid < 64) {
            int off = (1792 + tid) * 4;
            __builtin_amdgcn_global_load_lds(
                (const __attribute__((address_space(1))) unsigned*)(g + off),
                (__attribute__((address_space(3))) unsigned*)(lbase + off),
                16, 0, 0);
        }
    };

    stage2(0, e0);
    __syncthreads();   // buf0 (2 experts) + xts ready

    f32x4 acc[4][7];
    #pragma unroll
    for (int rf = 0; rf < 4; ++rf)
        #pragma unroll
        for (int t = 0; t < 7; ++t)
            acc[rf][t] = (f32x4){0.f, 0.f, 0.f, 0.f};

    // ---- one expert's compute: 1 b64 xv + per ksh {4 wpk b128, A-build, 7x(b128+4 MFMA)} ----
    auto do_expert = [&](const unsigned char* ebase, int ei) {
        u16x4 xq = *(const u16x4*)&xts[ei * 256 + wave * 64 + lrow * 4];
        float xv[4];
        #pragma unroll
        for (int rf = 0; rf < 4; ++rf) xv[rf] = bf2f(xq[rf]);

        #pragma unroll
        for (int ksh = 0; ksh < 2; ++ksh) {
            const float4* wpk = (const float4*)(ebase + 14336 + (ksh * 4 + kg) * 64);
            float4 wa = wpk[0];
            float4 wb = wpk[1];
            float4 ba = wpk[2];
            float4 bb = wpk[3];

            short8 afr[4];
            #pragma unroll
            for (int rf = 0; rf < 4; ++rf) {
                float xr = xv[rf];
                short8 a;
                a[0] = cvtbf(fmaxf(fmaf(xr, wa.x, ba.x), 0.f));
                a[1] = cvtbf(fmaxf(fmaf(xr, wa.y, ba.y), 0.f));
                a[2] = cvtbf(fmaxf(fmaf(xr, wa.z, ba.z), 0.f));
                a[3] = cvtbf(fmaxf(fmaf(xr, wa.w, ba.w), 0.f));
                a[4] = cvtbf(fmaxf(fmaf(xr, wb.x, bb.x), 0.f));
                a[5] = cvtbf(fmaxf(fmaf(xr, wb.y, bb.y), 0.f));
                a[6] = cvtbf(fmaxf(fmaf(xr, wb.z, bb.z), 0.f));
                a[7] = cvtbf(fmaxf(fmaf(xr, wb.w, bb.w), 0.f));
                afr[rf] = a;
            }

            __builtin_amdgcn_s_setprio(1);
            #pragma unroll
            for (int t = 0; t < 7; ++t) {
                short8 bf = *(const short8*)(ebase + ((ksh * 7 + t) << 10) + lane * 16);
                #pragma unroll
                for (int rf = 0; rf < 4; ++rf)
                    acc[rf][t] = __builtin_amdgcn_mfma_f32_16x16x32_bf16(afr[rf], bf, acc[rf][t], 0, 0, 0);
            }
            __builtin_amdgcn_s_setprio(0);
        }
    };

    int cur = 0;
    const int npairs = ne >> 1;   // ne is even (32 or 28)
    for (int p = 0; p < npairs; ++p) {
        if (p + 1 < npairs) stage2(cur ^ 1, e0 + 2 * (p + 1));   // prefetch next pair

        const unsigned char* bufc = smem + cur * (2 * EXPB);
        do_expert(bufc, 2 * p);            // two independent chains -> ILP within phase
        do_expert(bufc + EXPB, 2 * p + 1);

        __syncthreads();   // next pair landed during compute
        cur ^= 1;
    }

    // ---- epilogue: C/D col = lane&15, row = kg*4 + reg -> partials ----
    float* dst = part + (size_t)ks * (NB * NV);
    #pragma unroll
    for (int rf = 0; rf < 4; ++rf) {
        #pragma unroll
        for (int t = 0; t < 7; ++t) {
            int col = t * 16 + lrow;
            if (col < NV) {
                size_t base = (size_t)(row0 + wave * 64 + rf * 16 + kg * 4) * NV + col;
                #pragma unroll
                for (int r = 0; r < 4; ++r)
                    dst[base + (size_t)r * NV] = acc[rf][t][r];
            }
        }
    }
}

// ---------------- reduce: out = bias + sum_k part[k] (float4) ----------------
__global__ void reduce2(const float* __restrict__ part, float* __restrict__ out) {
    int i4 = blockIdx.x * 256 + threadIdx.x;   // < NB*NV/4 = 102400
    f32x4 s = *(const f32x4*)&g_bsum[(i4 % 25) * 4];
    size_t off = (size_t)i4 * 4;
    #pragma unroll 4
    for (int k = 0; k < ESPLIT; ++k)
        s += *(const f32x4*)&part[(size_t)k * (NB * NV) + off];
    *(f32x4*)&out[off] = s;
}

// ---------------- fallback (tiny ws): in-kernel convert + atomics ----------------
#define LDW 72
__global__ __launch_bounds__(256, 3) void moe_fallback(
    const float* __restrict__ x, const float* __restrict__ W1,
    const float* __restrict__ b1, const float* __restrict__ W2,
    float* __restrict__ dst)
{
    __shared__ unsigned short w2t[8192];
    const int tid  = threadIdx.x;
    const int lane = tid & 63;
    const int lrow = lane & 15;
    const int kg   = lane >> 4;
    const int wave = tid >> 6;
    const int row0 = blockIdx.x * 128 + wave * 32;
    const int e0 = blockIdx.y * 32;
    const int e1 = min(NE, e0 + 32);

    f32x4 acc[2][7];
    #pragma unroll
    for (int rf = 0; rf < 2; ++rf)
        #pragma unroll
        for (int t = 0; t < 7; ++t)
            acc[rf][t] = (f32x4){0.f, 0.f, 0.f, 0.f};

    const float* xr0 = x + (size_t)(row0 + lrow) * NE;
    const float* xr1 = x + (size_t)(row0 + 16 + lrow) * NE;

    for (int e = e0; e < e1; ++e) {
        __syncthreads();
        const float* src = W2 + (size_t)e * (HID * NV);
        unsigned* w2t32 = (unsigned*)w2t;
        #pragma unroll
        for (int k = 0; k < 13; ++k) {
            int i = tid + k * 256;
            if (i < (HID / 2) * NV) {
                int a3  = i / 400;
                int rem = i - a3 * 400;
                int bv  = rem >> 2;
                int c   = rem & 3;
                int hh2 = a3 * 4 + c;
                float f0 = src[(2 * hh2) * NV + bv];
                float f1 = src[(2 * hh2 + 1) * NV + bv];
                w2t32[bv * (LDW / 2) + hh2] = pkbf(f0, f1);
            }
        }
        __syncthreads();

        float xv0 = xr0[e];
        float xv1 = xr1[e];
        const float* w1p = W1 + e * HID;
        const float* b1p = b1 + e * HID;
        #pragma unroll
        for (int ksh = 0; ksh < 2; ++ksh) {
            const int hb = ksh * 32 + kg * 8;
            f32x4 w1lo = *(const f32x4*)(w1p + hb);
            f32x4 w1hi = *(const f32x4*)(w1p + hb + 4);
            f32x4 blo  = *(const f32x4*)(b1p + hb);
            f32x4 bhi  = *(const f32x4*)(b1p + hb + 4);
            short8 a0, a1;
            #pragma unroll
            for (int j = 0; j < 4; ++j) {
                a0[j]     = cvtbf(fmaxf(fmaf(xv0, w1lo[j], blo[j]), 0.f));
                a0[j + 4] = cvtbf(fmaxf(fmaf(xv0, w1hi[j], bhi[j]), 0.f));
                a1[j]     = cvtbf(fmaxf(fmaf(xv1, w1lo[j], blo[j]), 0.f));
                a1[j + 4] = cvtbf(fmaxf(fmaf(xv1, w1hi[j], bhi[j]), 0.f));
            }
            #pragma unroll
            for (int t = 0; t < 7; ++t) {
                short8 bf = *(const short8*)&w2t[(t * 16 + lrow) * LDW + hb];
                acc[0][t] = __builtin_amdgcn_mfma_f32_16x16x32_bf16(a0, bf, acc[0][t], 0, 0, 0);
                acc[1][t] = __builtin_amdgcn_mfma_f32_16x16x32_bf16(a1, bf, acc[1][t], 0, 0, 0);
            }
        }
    }

    #pragma unroll
    for (int rf = 0; rf < 2; ++rf) {
        #pragma unroll
        for (int t = 0; t < 7; ++t) {
            int col = t * 16 + lrow;
            if (col < NV) {
                size_t base = (size_t)(row0 + rf * 16 + kg * 4) * NV + col;
                #pragma unroll
                for (int r = 0; r < 4; ++r)
                    atomicAdd(&dst[base + (size_t)r * NV], acc[rf][t][r]);
            }
        }
    }
}

extern "C" void kernel_launch(void* const* d_in, const int* in_sizes, int n_in,
                              void* d_out, int out_size, void* d_ws, size_t ws_size,
                              hipStream_t stream) {
    const float* x  = (const float*)d_in[0];
    const float* W1 = (const float*)d_in[1];
    const float* b1 = (const float*)d_in[2];
    const float* W2 = (const float*)d_in[3];
    const float* b2 = (const float*)d_in[4];
    float* out = (float*)d_out;

    const size_t BLOB_BYTES = (size_t)NE * BLOBU * 4;        // 14,848,000
    const size_t PART_BYTES = (size_t)ESPLIT * NB * NV * 4;  // 52,428,800

    bias_kernel<<<NV, 256, 0, stream>>>(b2);

    if (ws_size >= BLOB_BYTES + PART_BYTES) {
        unsigned* blob = (unsigned*)d_ws;
        float* part = (float*)((char*)d_ws + BLOB_BYTES);
        prepass6<<<NE, 256, 0, stream>>>(W2, W1, b1, blob);
        moe9<<<512, 256, 0, stream>>>(x, blob, part);
        reduce2<<<(NB * NV / 4 + 255) / 256, 256, 0, stream>>>(part, out);
    } else {
        init_kernel<<<(NB * NV + 255) / 256, 256, 0, stream>>>(out);
        moe_fallback<<<dim3(NB / 128, ESPLIT), 256, 0, stream>>>(x, W1, b1, W2, out);
    }
}